// Round 1
// 902.111 us; speedup vs baseline: 1.4514x; 1.4514x over previous
//
#include <hip/hip_runtime.h>

// LowBitMLP on MI355X (gfx950).
// R3: replace the 128^2 two-barrier GEMM (m97-structure, measured 477 TF,
// MfmaUtil 19.7%) with the 256^2 8-phase schedule (m201 template):
//   - 256x256 tile, BK=64, 512 thr (2x4 waves, 128x64 C/wave), 128KB LDS
//   - 4 phases/K-tile: (k-half, m-half) -> 8/4/8/4 ds_read_b128 + 16 MFMA
//   - 1 half-unit (16KB) global_load_lds prefetch per phase, distance 3-4 ph
//   - counted s_waitcnt vmcnt(4) twice per K-tile (never 0 in steady state),
//     raw s_barrier (no compiler vmcnt(0) drain), setprio(1) around MFMA
// Ledger (steady state, tile t, phases P0..P3):
//   P0 stage A(t+1,k0); P1 stage B(t+1,k0); P2 stage A(t+1,k1); P3 stage B(t+1,k1)
//   gate kh1(t) at P1: newer = {A(t+1,k0),B(t+1,k0)} = 4 loads -> vmcnt(4)
//   gate kh0(t+1) at P3: newer = {A(t+1,k1),B(t+1,k1)} = 4 loads -> vmcnt(4)
//   WAR: each staged region's last reader finished >=2 barriers earlier.
//
// Memory plan (unchanged):
//   d_out: [0,32M) x_h f16; [32M,64M) tw1 f16   (dead before GEMM2 writes)
//   d_ws : [0,32M) tw2 f16; [32M,160M) h f16 (GEMM1 out, LN1+relu in place)

#define THRESH 0.1f
#define LN_EPS 1e-5f

typedef _Float16 f16x8 __attribute__((ext_vector_type(8)));
typedef float f32x4 __attribute__((ext_vector_type(4)));

typedef __attribute__((address_space(3))) void lds_void;
typedef const __attribute__((address_space(1))) void glob_void;

__device__ __forceinline__ void gld16(const void* g, void* l) {
  __builtin_amdgcn_global_load_lds((glob_void*)g, (lds_void*)l, 16, 0, 0);
}

// ---------------- elementwise prep ----------------

__global__ __launch_bounds__(256) void cvt_x_f16(const float* __restrict__ x,
                                                 _Float16* __restrict__ y) {
  const long i = ((long)blockIdx.x * 256 + threadIdx.x) * 8;
  const float4 v0 = *(const float4*)(x + i);
  const float4 v1 = *(const float4*)(x + i + 4);
  const float a[8] = {v0.x, v0.y, v0.z, v0.w, v1.x, v1.y, v1.z, v1.w};
  f16x8 o;
#pragma unroll
  for (int e = 0; e < 8; ++e) o[e] = (_Float16)a[e];
  *(f16x8*)(y + i) = o;
}

__global__ __launch_bounds__(256) void quant_w(const float* __restrict__ w,
                                               _Float16* __restrict__ t) {
  const long i = ((long)blockIdx.x * 256 + threadIdx.x) * 8;
  const float4 v0 = *(const float4*)(w + i);
  const float4 v1 = *(const float4*)(w + i + 4);
  const float a[8] = {v0.x, v0.y, v0.z, v0.w, v1.x, v1.y, v1.z, v1.w};
  f16x8 o;
#pragma unroll
  for (int e = 0; e < 8; ++e) {
    const float q = (fabsf(a[e]) < THRESH) ? 0.f : (a[e] > 0.f ? 1.f : -1.f);
    o[e] = (_Float16)q;
  }
  *(f16x8*)(t + i) = o;
}

// ---------------- 256^2 8-phase GEMM-BT: C = A(MxK) * B(NxK)^T, fused (acc+b)*s --------
// LDS layout: per buffer, per k-half, 16 fragment blocks of 16rows x 32k
// (1KB each, fragment-contiguous => conflict-free ds_read_b128; staging dest
// is linear chunk index => satisfies global_load_lds wave-uniform+lane*16).

#define BARF()                       \
  __builtin_amdgcn_s_barrier();      \
  asm volatile("" ::: "memory")
#define LGKM0() asm volatile("s_waitcnt lgkmcnt(0)" ::: "memory")
#define VMC4() asm volatile("s_waitcnt vmcnt(4)" ::: "memory")
#define VMC0() asm volatile("s_waitcnt vmcnt(0)" ::: "memory")

#define MFMA_QUAD(m0)                                                                        \
  __builtin_amdgcn_s_setprio(1);                                                             \
  _Pragma("unroll") for (int i = 0; i < 4; ++i)                                              \
  _Pragma("unroll") for (int j = 0; j < 4; ++j)                                              \
      acc[(m0) + i][j] = __builtin_amdgcn_mfma_f32_16x16x32_f16(af[i], bf[j],                \
                                                                acc[(m0) + i][j], 0, 0, 0); \
  __builtin_amdgcn_s_setprio(0)

template <bool OUT_F16>
__global__ __launch_bounds__(512, 2) void gemm256(const _Float16* __restrict__ A,
                                                  const _Float16* __restrict__ B,
                                                  void* __restrict__ C,
                                                  const float* __restrict__ bias,
                                                  const float* __restrict__ scale,
                                                  int N, int K) {
  __shared__ _Float16 sA[2][2][8192];  // [buf][khalf][16 frag * 512] = 64KB
  __shared__ _Float16 sB[2][2][8192];  // 64KB

  const int tid = threadIdx.x;
  const int lane = tid & 63;
  const int wave = tid >> 6;
  const int wm = wave >> 2;  // 0..1 -> C rows wm*128..+128
  const int wn = wave & 3;   // 0..3 -> C cols wn*64..+64
  const long row0 = (long)blockIdx.y * 256;
  const long col0 = (long)blockIdx.x * 256;

  // Staging: chunk c in [0,1024): frag mb=c>>6, row=mb*16+(c&15), koct=(c>>4)&3.
  const int c0 = tid, c1 = tid + 512;
  const _Float16* pA0 = A + (row0 + ((c0 >> 6) << 4) + (c0 & 15)) * (long)K + (((c0 >> 4) & 3) << 3);
  const _Float16* pA1 = A + (row0 + ((c1 >> 6) << 4) + (c1 & 15)) * (long)K + (((c1 >> 4) & 3) << 3);
  const _Float16* pB0 = B + (col0 + ((c0 >> 6) << 4) + (c0 & 15)) * (long)K + (((c0 >> 4) & 3) << 3);
  const _Float16* pB1 = B + (col0 + ((c1 >> 6) << 4) + (c1 & 15)) * (long)K + (((c1 >> 4) & 3) << 3);

#define STG_A(nx, kh, koff)                     \
  gld16(pA0 + (koff), &sA[nx][kh][c0 * 8]);     \
  gld16(pA1 + (koff), &sA[nx][kh][c1 * 8])
#define STG_B(nx, kh, koff)                     \
  gld16(pB0 + (koff), &sB[nx][kh][c0 * 8]);     \
  gld16(pB1 + (koff), &sB[nx][kh][c1 * 8])

  f32x4 acc[8][4] = {};
  const int nT = K >> 6;
  const int aoff = wm * 8 * 512 + lane * 8;  // elems; frag mf adds mf*512
  const int boff = wn * 4 * 512 + lane * 8;

  // Prologue: tile 0 -> buf 0. Gate kh0(0): newer = {A(0,k1),B(0,k1)} = 4 loads.
  STG_A(0, 0, 0);
  STG_B(0, 0, 0);
  STG_A(0, 1, 32);
  STG_B(0, 1, 32);
  VMC4();
  BARF();

  for (int t = 0; t < nT; ++t) {
    const int cur = t & 1, nx = cur ^ 1;
    const bool more = (t + 1 < nT);
    const int kn = (t + 1) << 6;

    f16x8 af[4], bf[4];

    // ---- P0: kh0, m-frags 0-3 (8 ds_read) ----
#pragma unroll
    for (int i = 0; i < 4; ++i) af[i] = *(const f16x8*)&sA[cur][0][aoff + i * 512];
#pragma unroll
    for (int j = 0; j < 4; ++j) bf[j] = *(const f16x8*)&sB[cur][0][boff + j * 512];
    if (more) { STG_A(nx, 0, kn); }
    BARF();
    LGKM0();
    MFMA_QUAD(0);
    BARF();

    // ---- P1: kh0, m-frags 4-7 (4 ds_read); gate kh1(t) ----
#pragma unroll
    for (int i = 0; i < 4; ++i) af[i] = *(const f16x8*)&sA[cur][0][aoff + (4 + i) * 512];
    if (more) {
      STG_B(nx, 0, kn);
      VMC4();  // A(t,k1),B(t,k1) landed; newer = A(t+1,k0),B(t+1,k0)
    } else {
      VMC0();  // last tile: nothing newer outstanding
    }
    BARF();
    LGKM0();
    MFMA_QUAD(4);
    BARF();

    // ---- P2: kh1, m-frags 0-3 (8 ds_read) ----
#pragma unroll
    for (int i = 0; i < 4; ++i) af[i] = *(const f16x8*)&sA[cur][1][aoff + i * 512];
#pragma unroll
    for (int j = 0; j < 4; ++j) bf[j] = *(const f16x8*)&sB[cur][1][boff + j * 512];
    if (more) { STG_A(nx, 1, kn + 32); }
    BARF();
    LGKM0();
    MFMA_QUAD(0);
    BARF();

    // ---- P3: kh1, m-frags 4-7 (4 ds_read); gate kh0(t+1) ----
#pragma unroll
    for (int i = 0; i < 4; ++i) af[i] = *(const f16x8*)&sA[cur][1][aoff + (4 + i) * 512];
    if (more) {
      STG_B(nx, 1, kn + 32);
      VMC4();  // A(t+1,k0),B(t+1,k0) landed; newer = A(t+1,k1),B(t+1,k1)
    }
    BARF();
    LGKM0();
    MFMA_QUAD(4);
    BARF();
  }

  // Epilogue: C/D layout col = lane&15, row = (lane>>4)*4 + reg.
  const int qd = lane >> 4, l16 = lane & 15;
#pragma unroll
  for (int nf = 0; nf < 4; ++nf) {
    const long c = col0 + wn * 64 + nf * 16 + l16;
    const float bb = bias[c];
    const float ss = scale[c];
#pragma unroll
    for (int mf = 0; mf < 8; ++mf) {
      const long r = row0 + wm * 128 + mf * 16 + qd * 4;
#pragma unroll
      for (int reg = 0; reg < 4; ++reg) {
        const float v = (acc[mf][nf][reg] + bb) * ss;
        if constexpr (OUT_F16)
          ((_Float16*)C)[(r + reg) * (long)N + c] = (_Float16)v;
        else
          ((float*)C)[(r + reg) * (long)N + c] = v;
      }
    }
  }
}

// ---------------- row LayerNorm kernels ----------------

// D = 8192, f16 in/out, LN*g+b then relu, in place. One block (256 thr) per row.
__global__ __launch_bounds__(256) void ln_relu_rows_f16(_Float16* __restrict__ h,
                                                        const float* __restrict__ g,
                                                        const float* __restrict__ b) {
  const int D = 8192;
  const long base = (long)blockIdx.x * D;
  const int tid = threadIdx.x;
  f16x8 v[4];
  float sum = 0.f, sq = 0.f;
#pragma unroll
  for (int c = 0; c < 4; ++c) {
    v[c] = *(const f16x8*)&h[base + c * 2048 + tid * 8];
#pragma unroll
    for (int e = 0; e < 8; ++e) {
      const float f = (float)v[c][e];
      sum += f;
      sq += f * f;
    }
  }
#pragma unroll
  for (int off = 32; off > 0; off >>= 1) {
    sum += __shfl_down(sum, off);
    sq += __shfl_down(sq, off);
  }
  __shared__ float rs[4], rq[4];
  const int wv = tid >> 6, ln = tid & 63;
  if (ln == 0) { rs[wv] = sum; rq[wv] = sq; }
  __syncthreads();
  sum = rs[0] + rs[1] + rs[2] + rs[3];
  sq = rq[0] + rq[1] + rq[2] + rq[3];
  const float mu = sum / D;
  const float rstd = rsqrtf(sq / D - mu * mu + LN_EPS);
#pragma unroll
  for (int c = 0; c < 4; ++c) {
    const int col = c * 2048 + tid * 8;
    f16x8 o;
#pragma unroll
    for (int e = 0; e < 8; ++e) {
      const float f = ((float)v[c][e] - mu) * rstd * g[col + e] + b[col + e];
      o[e] = (_Float16)fmaxf(f, 0.f);
    }
    *(f16x8*)&h[base + col] = o;
  }
}

// D = 2048, f32, LN*g+b IN PLACE on d_out. One block (256 thr) per row.
__global__ __launch_bounds__(256) void ln_rows_f32_inplace(float* __restrict__ io,
                                                           const float* __restrict__ g,
                                                           const float* __restrict__ b) {
  const int D = 2048;
  const long base = (long)blockIdx.x * D;
  const int tid = threadIdx.x;
  const float4 v0 = *(const float4*)&io[base + tid * 8];
  const float4 v1 = *(const float4*)&io[base + tid * 8 + 4];
  const float a[8] = {v0.x, v0.y, v0.z, v0.w, v1.x, v1.y, v1.z, v1.w};
  float sum = 0.f, sq = 0.f;
#pragma unroll
  for (int e = 0; e < 8; ++e) {
    sum += a[e];
    sq += a[e] * a[e];
  }
#pragma unroll
  for (int off = 32; off > 0; off >>= 1) {
    sum += __shfl_down(sum, off);
    sq += __shfl_down(sq, off);
  }
  __shared__ float rs[4], rq[4];
  const int wv = tid >> 6, ln = tid & 63;
  if (ln == 0) { rs[wv] = sum; rq[wv] = sq; }
  __syncthreads();
  sum = rs[0] + rs[1] + rs[2] + rs[3];
  sq = rq[0] + rq[1] + rq[2] + rq[3];
  const float mu = sum / D;
  const float rstd = rsqrtf(sq / D - mu * mu + LN_EPS);
  const int col = tid * 8;
  float o[8];
#pragma unroll
  for (int e = 0; e < 8; ++e) o[e] = (a[e] - mu) * rstd * g[col + e] + b[col + e];
  *(float4*)&io[base + col] = make_float4(o[0], o[1], o[2], o[3]);
  *(float4*)&io[base + col + 4] = make_float4(o[4], o[5], o[6], o[7]);
}

// ---------------- launch ----------------

extern "C" void kernel_launch(void* const* d_in, const int* in_sizes, int n_in,
                              void* d_out, int out_size, void* d_ws, size_t ws_size,
                              hipStream_t stream) {
  const float* x    = (const float*)d_in[0];
  const float* w1   = (const float*)d_in[1];
  const float* b1   = (const float*)d_in[2];
  const float* s1   = (const float*)d_in[3];
  const float* w2   = (const float*)d_in[4];
  const float* b2   = (const float*)d_in[5];
  const float* s2   = (const float*)d_in[6];
  const float* ln1g = (const float*)d_in[7];
  const float* ln1b = (const float*)d_in[8];
  const float* outg = (const float*)d_in[9];
  const float* outb = (const float*)d_in[10];

  const int N = 8192, D_IN = 2048, D_H = 8192, D_OUT = 2048;
  const size_t MB = 1024 * 1024;
  // Scratch phase-1 buffers live in d_out (64MB); dead before GEMM2 writes it.
  char* ob = (char*)d_out;
  _Float16* xh  = (_Float16*)(ob);            // 32MB
  _Float16* tw1 = (_Float16*)(ob + 32 * MB);  // 32MB
  // Persistent-through-GEMM2 buffers in d_ws (160MB used).
  char* ws = (char*)d_ws;
  _Float16* tw2 = (_Float16*)(ws);            // 32MB
  _Float16* h   = (_Float16*)(ws + 32 * MB);  // 128MB

  // elementwise prep: each block handles 2048 elems
  cvt_x_f16<<<(N * D_IN) / 2048, 256, 0, stream>>>(x, xh);
  quant_w<<<(D_H * D_IN) / 2048, 256, 0, stream>>>(w1, tw1);
  quant_w<<<(D_OUT * D_H) / 2048, 256, 0, stream>>>(w2, tw2);

  // layer 1: h = (x @ tw1^T + b1) * s1   -> f16
  gemm256<true><<<dim3(D_H / 256, N / 256), 512, 0, stream>>>(xh, tw1, h, b1, s1, D_H, D_IN);
  // LN + relu in place
  ln_relu_rows_f16<<<N, 256, 0, stream>>>(h, ln1g, ln1b);

  // layer 2: (h @ tw2^T + b2) * s2 -> f32, straight into d_out (xh/tw1 dead)
  gemm256<false><<<dim3(D_OUT / 256, N / 256), 512, 0, stream>>>(h, tw2, d_out, b2, s2, D_OUT, D_H);
  // final LN in place on d_out
  ln_rows_f32_inplace<<<N, 256, 0, stream>>>((float*)d_out, outg, outb);
}